// Round 1
// baseline (6470.403 us; speedup 1.0000x reference)
//
#include <hip/hip_runtime.h>
#include <cstdint>
#include <cstddef>

#define BN 64
#define TN 512
#define DN 256
#define UN 256
#define NC 768            // 3*UN, order: r | z | h
#define SLOTS (TN + 5)    // slots TN..TN+3 = initial states, TN+4 = zero slot
#define ZSLOT (TN + 4)

__device__ __forceinline__ float sigm(float x) {
  return 1.0f / (1.0f + __expf(-x));
}
__device__ __forceinline__ float tanh_fast(float x) {
  float e = __expf(-2.0f * x);
  return 2.0f / (1.0f + e) - 1.0f;
}

// ---------------- kernel 0: concat weights + biases ----------------
__global__ __launch_bounds__(256) void build_wcat(
    const float* __restrict__ Wr, const float* __restrict__ Wz, const float* __restrict__ Wh,
    const float* __restrict__ br, const float* __restrict__ bz, const float* __restrict__ bh,
    float* __restrict__ wcat, float* __restrict__ bias)
{
  int idx = blockIdx.x * 256 + threadIdx.x;
  if (idx < DN * NC) {
    int k = idx / NC, c = idx % NC;
    float v;
    if (c < 256)      v = Wr[k * UN + c];
    else if (c < 512) v = Wz[k * UN + (c - 256)];
    else              v = Wh[k * UN + (c - 512)];
    wcat[idx] = v;
  }
  if (idx < NC) {
    bias[idx] = (idx < 256) ? br[idx] : ((idx < 512) ? bz[idx - 256] : bh[idx - 512]);
  }
}

// ---------------- kernel 1: P = X @ Wcat + bias  (fp32, LDS-tiled) ----------------
__global__ __launch_bounds__(256) void gemm_xw(
    const float* __restrict__ X, const float* __restrict__ Wc,
    const float* __restrict__ bias, float* __restrict__ P)
{
  __shared__ float As[32][68];   // [k][m], padded stride 68 (16B-aligned rows, breaks pow2 conflicts)
  __shared__ float Bs[32][64];   // [k][n]
  const int tid = threadIdx.x;
  const int m0 = blockIdx.x * 64;
  const int n0 = blockIdx.y * 64;
  const int ty = tid >> 4, tx = tid & 15;
  float acc[4][4] = {};

  const int ar = tid >> 3;         // 0..31
  const int ak = (tid & 7) * 4;    // 0,4,..,28
  const int bk = tid >> 4;         // 0..15
  const int bn = (tid & 15) * 4;   // 0,4,..,60

  for (int k0 = 0; k0 < DN; k0 += 32) {
    float4 a0 = *(const float4*)(X + (size_t)(m0 + ar) * DN + k0 + ak);
    float4 a1 = *(const float4*)(X + (size_t)(m0 + 32 + ar) * DN + k0 + ak);
    As[ak + 0][ar] = a0.x; As[ak + 1][ar] = a0.y; As[ak + 2][ar] = a0.z; As[ak + 3][ar] = a0.w;
    As[ak + 0][32 + ar] = a1.x; As[ak + 1][32 + ar] = a1.y; As[ak + 2][32 + ar] = a1.z; As[ak + 3][32 + ar] = a1.w;
    *(float4*)&Bs[bk][bn]      = *(const float4*)(Wc + (size_t)(k0 + bk) * NC + n0 + bn);
    *(float4*)&Bs[bk + 16][bn] = *(const float4*)(Wc + (size_t)(k0 + bk + 16) * NC + n0 + bn);
    __syncthreads();
#pragma unroll
    for (int kk = 0; kk < 32; kk++) {
      float4 av = *(const float4*)&As[kk][ty * 4];
      float4 bv = *(const float4*)&Bs[kk][tx * 4];
      acc[0][0] += av.x * bv.x; acc[0][1] += av.x * bv.y; acc[0][2] += av.x * bv.z; acc[0][3] += av.x * bv.w;
      acc[1][0] += av.y * bv.x; acc[1][1] += av.y * bv.y; acc[1][2] += av.y * bv.z; acc[1][3] += av.y * bv.w;
      acc[2][0] += av.z * bv.x; acc[2][1] += av.z * bv.y; acc[2][2] += av.z * bv.z; acc[2][3] += av.z * bv.w;
      acc[3][0] += av.w * bv.x; acc[3][1] += av.w * bv.y; acc[3][2] += av.w * bv.z; acc[3][3] += av.w * bv.w;
    }
    __syncthreads();
  }
  float4 bb = *(const float4*)(bias + n0 + tx * 4);
#pragma unroll
  for (int i = 0; i < 4; i++) {
    float4 o;
    o.x = acc[i][0] + bb.x; o.y = acc[i][1] + bb.y;
    o.z = acc[i][2] + bb.z; o.w = acc[i][3] + bb.w;
    *(float4*)(P + (size_t)(m0 + ty * 4 + i) * NC + n0 + tx * 4) = o;
  }
}

// ---------------- kernel 2: the recurrence, one block per batch ----------------
// thread = (g, u): g = tid>>8 in [0,4) owns k-range [64g, 64g+64); u = tid&255 = output col.
__global__ __launch_bounds__(1024) void recurrent_kernel(
    const float* __restrict__ P,
    const float* __restrict__ Ur, const float* __restrict__ Uz, const float* __restrict__ Uh,
    const int* __restrict__ dep, const int* __restrict__ mask,
    const float* __restrict__ init,
    float* __restrict__ out,
    float* __restrict__ buf_s, float* __restrict__ buf_pr, float* __restrict__ buf_pz)
{
  const int b = blockIdx.x;
  const int tid = threadIdx.x;
  const int g = tid >> 8;
  const int u = tid & 255;

  // --- weights in VGPRs: column u, k in [64g, 64g+64) ---
  float wr[64], wz[64], wh[64];
  {
    const float* p0 = Ur + (size_t)(64 * g) * UN + u;
    const float* p1 = Uz + (size_t)(64 * g) * UN + u;
    const float* p2 = Uh + (size_t)(64 * g) * UN + u;
#pragma unroll
    for (int kk = 0; kk < 64; kk++) {
      wr[kk] = p0[(size_t)kk * UN];
      wz[kk] = p1[(size_t)kk * UN];
      wh[kk] = p2[(size_t)kk * UN];
    }
  }

  __shared__ float ls[4][256], lpr[4][256], lpz[4][256];
  __shared__ float lx[NC];
  __shared__ float rs[256], hs[256], zv[256], hv[256];
  __shared__ float red0[4][256], red1[4][256];
  __shared__ float scur[256], prcur[256], pzcur[256];
  __shared__ int eff[TN];
  __shared__ int mloc[TN];
  __shared__ int deploc[TN * 3];

  for (int i = tid; i < TN; i += 1024) mloc[i] = mask[b * TN + i];
  for (int i = tid; i < TN * 3; i += 1024) deploc[i] = dep[i];

  const size_t bufBase = (size_t)b * SLOTS * UN;

  // prologue: stage initial states, zero slot, current-state LDS
  {
    float v = init[((size_t)g * BN + b) * UN + u];
    ls[g][u] = v;
    buf_s[bufBase + (size_t)(TN + g) * UN + u] = v;
    if (tid < 256) {
      scur[u] = 0.0f; prcur[u] = 0.0f; pzcur[u] = 0.0f;
      buf_s[bufBase + (size_t)ZSLOT * UN + u] = 0.0f;
      buf_pr[bufBase + (size_t)ZSLOT * UN + u] = 0.0f;
      buf_pz[bufBase + (size_t)ZSLOT * UN + u] = 0.0f;
    }
  }
  __syncthreads();

  // initial-state projections through Ur and Uz
#pragma unroll 1
  for (int gg = 0; gg < 4; gg++) {
    float ar0 = 0, ar1 = 0, ar2 = 0, ar3 = 0, az0 = 0, az1 = 0, az2 = 0, az3 = 0;
    const float4* sv4 = (const float4*)&ls[gg][64 * g];
#pragma unroll
    for (int kk = 0; kk < 16; kk++) {
      float4 v = sv4[kk];
      ar0 += v.x * wr[4 * kk];     az0 += v.x * wz[4 * kk];
      ar1 += v.y * wr[4 * kk + 1]; az1 += v.y * wz[4 * kk + 1];
      ar2 += v.z * wr[4 * kk + 2]; az2 += v.z * wz[4 * kk + 2];
      ar3 += v.w * wr[4 * kk + 3]; az3 += v.w * wz[4 * kk + 3];
    }
    red0[g][u] = (ar0 + ar1) + (ar2 + ar3);
    red1[g][u] = (az0 + az1) + (az2 + az3);
    __syncthreads();
    if (tid < 256) {
      buf_pr[bufBase + (size_t)(TN + gg) * UN + u] = red0[0][u] + red0[1][u] + red0[2][u] + red0[3][u];
      buf_pz[bufBase + (size_t)(TN + gg) * UN + u] = red1[0][u] + red1[1][u] + red1[2][u] + red1[3][u];
    }
    __syncthreads();
  }

  const size_t outB = (size_t)b * TN * UN;
  const size_t pB = (size_t)b * TN * NC;

#pragma unroll 1
  for (int t = 0; t < TN; t++) {
    const int m = mloc[t];   // block-uniform
    if (m == 0) {
      if (tid < 256) out[outB + (size_t)t * UN + u] = 0.0f;
      if (tid == 0) eff[t] = (t == 0) ? ZSLOT : eff[t - 1];
      __syncthreads();
      continue;
    }
    // ---- A: gather 4 source states + cached projections + x-row ----
    if (t > 0 && g == 0) {
      ls[0][u] = scur[u]; lpr[0][u] = prcur[u]; lpz[0][u] = pzcur[u];
    } else {
      int src = (t == 0) ? (TN + g) : eff[deploc[(t - 1) * 3 + (g - 1)]];
      size_t base = bufBase + (size_t)src * UN + u;
      ls[g][u]  = buf_s[base];
      lpr[g][u] = buf_pr[base];
      lpz[g][u] = buf_pz[base];
    }
    if (tid < NC) lx[tid] = P[pB + (size_t)t * NC + tid];
    __syncthreads();
    // ---- A': gates (elementwise) ----
    if (tid < 256) {
      float s0 = ls[0][u], s1 = ls[1][u], s2 = ls[2][u], s3 = ls[3][u];
      float xr = lx[u];
      float r0 = sigm(xr + lpr[0][u]);
      float r1 = sigm(xr + lpr[1][u]);
      float r2 = sigm(xr + lpr[2][u]);
      float r3 = sigm(xr + lpr[3][u]);
      rs[u] = r0 * s0 + r1 * s1 + r2 * s2 + r3 * s3;
      hs[u] = (s0 + s1) + (s2 + s3);
      zv[u] = sigm(lx[256 + u] + ((lpz[0][u] + lpz[1][u]) + (lpz[2][u] + lpz[3][u])));
    }
    __syncthreads();
    // ---- B: live matvec rs @ Uh ----
    {
      float a0 = 0, a1 = 0, a2 = 0, a3 = 0;
      const float4* v4 = (const float4*)&rs[64 * g];
#pragma unroll
      for (int kk = 0; kk < 16; kk++) {
        float4 v = v4[kk];
        a0 += v.x * wh[4 * kk];     a1 += v.y * wh[4 * kk + 1];
        a2 += v.z * wh[4 * kk + 2]; a3 += v.w * wh[4 * kk + 3];
      }
      red0[g][u] = (a0 + a1) + (a2 + a3);
    }
    __syncthreads();
    // ---- C: h, output ----
    if (tid < 256) {
      float ht = tanh_fast(lx[512 + u] + ((red0[0][u] + red0[1][u]) + (red0[2][u] + red0[3][u])));
      float z = zv[u];
      float h = z * hs[u] * 0.25f + (1.0f - z) * ht;
      hv[u] = h; scur[u] = h;
      out[outB + (size_t)t * UN + u] = h;
    }
    __syncthreads();
    // ---- D: projections of the new state through Ur and Uz ----
    {
      float ar0 = 0, ar1 = 0, ar2 = 0, ar3 = 0, az0 = 0, az1 = 0, az2 = 0, az3 = 0;
      const float4* v4 = (const float4*)&hv[64 * g];
#pragma unroll
      for (int kk = 0; kk < 16; kk++) {
        float4 v = v4[kk];
        ar0 += v.x * wr[4 * kk];     az0 += v.x * wz[4 * kk];
        ar1 += v.y * wr[4 * kk + 1]; az1 += v.y * wz[4 * kk + 1];
        ar2 += v.z * wr[4 * kk + 2]; az2 += v.z * wz[4 * kk + 2];
        ar3 += v.w * wr[4 * kk + 3]; az3 += v.w * wz[4 * kk + 3];
      }
      red0[g][u] = (ar0 + ar1) + (ar2 + ar3);
      red1[g][u] = (az0 + az1) + (az2 + az3);
    }
    __syncthreads();
    // ---- E: commit state + cached projections ----
    if (tid < 256) {
      float prn = (red0[0][u] + red0[1][u]) + (red0[2][u] + red0[3][u]);
      float pzn = (red1[0][u] + red1[1][u]) + (red1[2][u] + red1[3][u]);
      prcur[u] = prn; pzcur[u] = pzn;
      size_t base = bufBase + (size_t)t * UN + u;
      buf_s[base]  = hv[u];
      buf_pr[base] = prn;
      buf_pz[base] = pzn;
    }
    if (tid == 0) eff[t] = t;
    __syncthreads();
  }

  // epilogue: last_out, last_state
  if (tid < 256) {
    float lst = scur[u];
    out[(size_t)BN * TN * UN + (size_t)b * UN + u] = mloc[TN - 1] ? lst : 0.0f;
    out[(size_t)BN * TN * UN + (size_t)BN * UN + (size_t)b * UN + u] = lst;
  }
}

extern "C" void kernel_launch(void* const* d_in, const int* in_sizes, int n_in,
                              void* d_out, int out_size, void* d_ws, size_t ws_size,
                              hipStream_t stream) {
  const float* inputs       = (const float*)d_in[0];
  const int*   dependencies = (const int*)d_in[1];
  const int*   mask         = (const int*)d_in[2];
  const float* initial      = (const float*)d_in[3];
  const float* Wz = (const float*)d_in[4];
  const float* Wr = (const float*)d_in[5];
  const float* Wh = (const float*)d_in[6];
  const float* Uz = (const float*)d_in[7];
  const float* Ur = (const float*)d_in[8];
  const float* Uh = (const float*)d_in[9];
  const float* bz = (const float*)d_in[10];
  const float* br = (const float*)d_in[11];
  const float* bh = (const float*)d_in[12];

  float* out = (float*)d_out;
  float* ws  = (float*)d_ws;
  float* wcat    = ws;                                   // 256*768
  float* bias    = wcat + (size_t)DN * NC;               // 768
  float* precomp = bias + NC;                            // B*T*768
  float* buf_s   = precomp + (size_t)BN * TN * NC;       // B*SLOTS*256 each
  float* buf_pr  = buf_s + (size_t)BN * SLOTS * UN;
  float* buf_pz  = buf_pr + (size_t)BN * SLOTS * UN;

  build_wcat<<<(DN * NC + 255) / 256, 256, 0, stream>>>(Wr, Wz, Wh, br, bz, bh, wcat, bias);
  gemm_xw<<<dim3(BN * TN / 64, NC / 64), 256, 0, stream>>>(inputs, wcat, bias, precomp);
  recurrent_kernel<<<BN, 1024, 0, stream>>>(precomp, Ur, Uz, Uh, dependencies, mask, initial,
                                            out, buf_s, buf_pr, buf_pz);
}

// Round 2
// 2058.163 us; speedup vs baseline: 3.1438x; 3.1438x over previous
//
#include <hip/hip_runtime.h>
#include <cstdint>
#include <cstddef>

#define BN 64
#define TN 512
#define DN 256
#define UN 256
#define NC 768            // 3*UN, order: r | z | h
#define SLOTS (TN + 5)    // slots TN..TN+3 = initial states, TN+4 = zero slot
#define ZSLOT (TN + 4)

__device__ __forceinline__ float sigm(float x) {
  return 1.0f / (1.0f + __expf(-x));
}
__device__ __forceinline__ float tanh_fast(float x) {
  float e = __expf(-2.0f * x);
  return 2.0f / (1.0f + e) - 1.0f;
}

// ---------------- kernel 0: concat weights + biases ----------------
__global__ __launch_bounds__(256) void build_wcat(
    const float* __restrict__ Wr, const float* __restrict__ Wz, const float* __restrict__ Wh,
    const float* __restrict__ br, const float* __restrict__ bz, const float* __restrict__ bh,
    float* __restrict__ wcat, float* __restrict__ bias)
{
  int idx = blockIdx.x * 256 + threadIdx.x;
  if (idx < DN * NC) {
    int k = idx / NC, c = idx % NC;
    float v;
    if (c < 256)      v = Wr[k * UN + c];
    else if (c < 512) v = Wz[k * UN + (c - 256)];
    else              v = Wh[k * UN + (c - 512)];
    wcat[idx] = v;
  }
  if (idx < NC) {
    bias[idx] = (idx < 256) ? br[idx] : ((idx < 512) ? bz[idx - 256] : bh[idx - 512]);
  }
}

// ---------------- kernel 1: P = X @ Wcat + bias  (fp32, LDS-tiled) ----------------
__global__ __launch_bounds__(256) void gemm_xw(
    const float* __restrict__ X, const float* __restrict__ Wc,
    const float* __restrict__ bias, float* __restrict__ P)
{
  __shared__ float As[32][68];
  __shared__ float Bs[32][64];
  const int tid = threadIdx.x;
  const int m0 = blockIdx.x * 64;
  const int n0 = blockIdx.y * 64;
  const int ty = tid >> 4, tx = tid & 15;
  float acc[4][4] = {};

  const int ar = tid >> 3;
  const int ak = (tid & 7) * 4;
  const int bk = tid >> 4;
  const int bn = (tid & 15) * 4;

  for (int k0 = 0; k0 < DN; k0 += 32) {
    float4 a0 = *(const float4*)(X + (size_t)(m0 + ar) * DN + k0 + ak);
    float4 a1 = *(const float4*)(X + (size_t)(m0 + 32 + ar) * DN + k0 + ak);
    As[ak + 0][ar] = a0.x; As[ak + 1][ar] = a0.y; As[ak + 2][ar] = a0.z; As[ak + 3][ar] = a0.w;
    As[ak + 0][32 + ar] = a1.x; As[ak + 1][32 + ar] = a1.y; As[ak + 2][32 + ar] = a1.z; As[ak + 3][32 + ar] = a1.w;
    *(float4*)&Bs[bk][bn]      = *(const float4*)(Wc + (size_t)(k0 + bk) * NC + n0 + bn);
    *(float4*)&Bs[bk + 16][bn] = *(const float4*)(Wc + (size_t)(k0 + bk + 16) * NC + n0 + bn);
    __syncthreads();
#pragma unroll
    for (int kk = 0; kk < 32; kk++) {
      float4 av = *(const float4*)&As[kk][ty * 4];
      float4 bv = *(const float4*)&Bs[kk][tx * 4];
      acc[0][0] += av.x * bv.x; acc[0][1] += av.x * bv.y; acc[0][2] += av.x * bv.z; acc[0][3] += av.x * bv.w;
      acc[1][0] += av.y * bv.x; acc[1][1] += av.y * bv.y; acc[1][2] += av.y * bv.z; acc[1][3] += av.y * bv.w;
      acc[2][0] += av.z * bv.x; acc[2][1] += av.z * bv.y; acc[2][2] += av.z * bv.z; acc[2][3] += av.z * bv.w;
      acc[3][0] += av.w * bv.x; acc[3][1] += av.w * bv.y; acc[3][2] += av.w * bv.z; acc[3][3] += av.w * bv.w;
    }
    __syncthreads();
  }
  float4 bb = *(const float4*)(bias + n0 + tx * 4);
#pragma unroll
  for (int i = 0; i < 4; i++) {
    float4 o;
    o.x = acc[i][0] + bb.x; o.y = acc[i][1] + bb.y;
    o.z = acc[i][2] + bb.z; o.w = acc[i][3] + bb.w;
    *(float4*)(P + (size_t)(m0 + ty * 4 + i) * NC + n0 + tx * 4) = o;
  }
}

// ---------------- kernel 2: the recurrence, one block per batch ----------------
// B-phase roles: thread = (g = tid>>8, u = tid&255); Uh col u, k in [64g, 64g+64) in VGPRs.
// D-phase roles: thread = (qd = tid>>6, cols [cd, cd+4) = 4*(tid&63)); Ur/Uz streamed from L2.
__global__ __launch_bounds__(1024, 4) void recurrent_kernel(
    const float* __restrict__ P,
    const float* __restrict__ Ur, const float* __restrict__ Uz, const float* __restrict__ Uh,
    const int* __restrict__ dep, const int* __restrict__ mask,
    const float* __restrict__ init,
    float* __restrict__ out,
    float* __restrict__ buf_s, float* __restrict__ buf_pr, float* __restrict__ buf_pz)
{
  const int b = blockIdx.x;
  const int tid = threadIdx.x;
  const int g = tid >> 8;
  const int u = tid & 255;
  const int qd = tid >> 6;          // 0..15, wave-uniform (wave = 64 consecutive tids)
  const int cd = (tid & 63) * 4;    // 4 consecutive output cols

  // --- Uh in VGPRs: column u, k in [64g, 64g+64) --- (64 fp32; fits 128-VGPR budget)
  float wh[64];
  {
    const float* p2 = Uh + (size_t)(64 * g) * UN + u;
#pragma unroll
    for (int kk = 0; kk < 64; kk++) {
      wh[kk] = p2[(size_t)kk * UN];
    }
  }

  __shared__ float ls[4][256], lpr[4][256], lpz[4][256];
  __shared__ float lx[NC];
  __shared__ float rs[256], hs[256], zv[256], hv[256];
  __shared__ float red0[4][256];
  __shared__ float reddR[16][256], reddZ[16][256];
  __shared__ float scur[256], prcur[256], pzcur[256];
  __shared__ int eff[TN];
  __shared__ int mloc[TN];
  __shared__ int deploc[TN * 3];

  for (int i = tid; i < TN; i += 1024) mloc[i] = mask[b * TN + i];
  for (int i = tid; i < TN * 3; i += 1024) deploc[i] = dep[i];

  const size_t bufBase = (size_t)b * SLOTS * UN;

  // prologue: stage initial states, zero slot, current-state LDS
  {
    float v = init[((size_t)g * BN + b) * UN + u];
    ls[g][u] = v;
    buf_s[bufBase + (size_t)(TN + g) * UN + u] = v;
    if (tid < 256) {
      scur[u] = 0.0f; prcur[u] = 0.0f; pzcur[u] = 0.0f;
      buf_s[bufBase + (size_t)ZSLOT * UN + u] = 0.0f;
      buf_pr[bufBase + (size_t)ZSLOT * UN + u] = 0.0f;
      buf_pz[bufBase + (size_t)ZSLOT * UN + u] = 0.0f;
    }
  }
  __syncthreads();

  // initial-state projections through Ur and Uz (streamed D-phase)
#pragma unroll 1
  for (int gg = 0; gg < 4; gg++) {
    float4 arA = {0, 0, 0, 0}, azA = {0, 0, 0, 0};
    const float* bR = Ur + (size_t)(qd * 16) * UN + cd;
    const float* bZ = Uz + (size_t)(qd * 16) * UN + cd;
#pragma unroll 4
    for (int kk = 0; kk < 16; kk++) {
      float hk = ls[gg][qd * 16 + kk];
      float4 w1 = *(const float4*)(bR + (size_t)kk * UN);
      float4 w2 = *(const float4*)(bZ + (size_t)kk * UN);
      arA.x = fmaf(hk, w1.x, arA.x); arA.y = fmaf(hk, w1.y, arA.y);
      arA.z = fmaf(hk, w1.z, arA.z); arA.w = fmaf(hk, w1.w, arA.w);
      azA.x = fmaf(hk, w2.x, azA.x); azA.y = fmaf(hk, w2.y, azA.y);
      azA.z = fmaf(hk, w2.z, azA.z); azA.w = fmaf(hk, w2.w, azA.w);
    }
    *(float4*)&reddR[qd][cd] = arA;
    *(float4*)&reddZ[qd][cd] = azA;
    __syncthreads();
    if (tid < 256) {
      float prn = 0.0f, pzn = 0.0f;
#pragma unroll
      for (int q = 0; q < 16; q++) { prn += reddR[q][tid]; pzn += reddZ[q][tid]; }
      buf_pr[bufBase + (size_t)(TN + gg) * UN + tid] = prn;
      buf_pz[bufBase + (size_t)(TN + gg) * UN + tid] = pzn;
    }
    __syncthreads();
  }

  const size_t outB = (size_t)b * TN * UN;
  const size_t pB = (size_t)b * TN * NC;

#pragma unroll 1
  for (int t = 0; t < TN; t++) {
    const int m = mloc[t];   // block-uniform
    if (m == 0) {
      if (tid < 256) out[outB + (size_t)t * UN + u] = 0.0f;
      if (tid == 0) eff[t] = (t == 0) ? ZSLOT : eff[t - 1];
      __syncthreads();
      continue;
    }
    // ---- A: gather 4 source states + cached projections + x-row ----
    if (t > 0 && g == 0) {
      ls[0][u] = scur[u]; lpr[0][u] = prcur[u]; lpz[0][u] = pzcur[u];
    } else {
      int src = (t == 0) ? (TN + g) : eff[deploc[(t - 1) * 3 + (g - 1)]];
      size_t base = bufBase + (size_t)src * UN + u;
      ls[g][u]  = buf_s[base];
      lpr[g][u] = buf_pr[base];
      lpz[g][u] = buf_pz[base];
    }
    if (tid < NC) lx[tid] = P[pB + (size_t)t * NC + tid];
    __syncthreads();
    // ---- A': gates (elementwise) ----
    if (tid < 256) {
      float s0 = ls[0][u], s1 = ls[1][u], s2 = ls[2][u], s3 = ls[3][u];
      float xr = lx[u];
      float r0 = sigm(xr + lpr[0][u]);
      float r1 = sigm(xr + lpr[1][u]);
      float r2 = sigm(xr + lpr[2][u]);
      float r3 = sigm(xr + lpr[3][u]);
      rs[u] = r0 * s0 + r1 * s1 + r2 * s2 + r3 * s3;
      hs[u] = (s0 + s1) + (s2 + s3);
      zv[u] = sigm(lx[256 + u] + ((lpz[0][u] + lpz[1][u]) + (lpz[2][u] + lpz[3][u])));
    }
    __syncthreads();
    // ---- B: live matvec rs @ Uh (register-resident Uh) ----
    {
      float a0 = 0, a1 = 0, a2 = 0, a3 = 0;
      const float4* v4 = (const float4*)&rs[64 * g];
#pragma unroll
      for (int kk = 0; kk < 16; kk++) {
        float4 v = v4[kk];
        a0 += v.x * wh[4 * kk];     a1 += v.y * wh[4 * kk + 1];
        a2 += v.z * wh[4 * kk + 2]; a3 += v.w * wh[4 * kk + 3];
      }
      red0[g][u] = (a0 + a1) + (a2 + a3);
    }
    __syncthreads();
    // ---- C: h, output ----
    if (tid < 256) {
      float ht = tanh_fast(lx[512 + u] + ((red0[0][u] + red0[1][u]) + (red0[2][u] + red0[3][u])));
      float z = zv[u];
      float h = z * hs[u] * 0.25f + (1.0f - z) * ht;
      hv[u] = h; scur[u] = h;
      out[outB + (size_t)t * UN + u] = h;
    }
    __syncthreads();
    // ---- D: projections of new state through Ur|Uz, streamed from L2 ----
    {
      float4 arA = {0, 0, 0, 0}, azA = {0, 0, 0, 0};
      const float* bR = Ur + (size_t)(qd * 16) * UN + cd;
      const float* bZ = Uz + (size_t)(qd * 16) * UN + cd;
#pragma unroll 4
      for (int kk = 0; kk < 16; kk++) {
        float hk = hv[qd * 16 + kk];
        float4 w1 = *(const float4*)(bR + (size_t)kk * UN);
        float4 w2 = *(const float4*)(bZ + (size_t)kk * UN);
        arA.x = fmaf(hk, w1.x, arA.x); arA.y = fmaf(hk, w1.y, arA.y);
        arA.z = fmaf(hk, w1.z, arA.z); arA.w = fmaf(hk, w1.w, arA.w);
        azA.x = fmaf(hk, w2.x, azA.x); azA.y = fmaf(hk, w2.y, azA.y);
        azA.z = fmaf(hk, w2.z, azA.z); azA.w = fmaf(hk, w2.w, azA.w);
      }
      *(float4*)&reddR[qd][cd] = arA;
      *(float4*)&reddZ[qd][cd] = azA;
    }
    __syncthreads();
    // ---- E: commit state + cached projections ----
    if (tid < 256) {
      float prn = 0.0f, pzn = 0.0f;
#pragma unroll
      for (int q = 0; q < 16; q++) { prn += reddR[q][tid]; pzn += reddZ[q][tid]; }
      prcur[tid] = prn; pzcur[tid] = pzn;
      size_t base = bufBase + (size_t)t * UN + tid;
      buf_s[base]  = hv[tid];
      buf_pr[base] = prn;
      buf_pz[base] = pzn;
    }
    if (tid == 0) eff[t] = t;
    __syncthreads();
  }

  // epilogue: last_out, last_state
  if (tid < 256) {
    float lst = scur[u];
    out[(size_t)BN * TN * UN + (size_t)b * UN + u] = mloc[TN - 1] ? lst : 0.0f;
    out[(size_t)BN * TN * UN + (size_t)BN * UN + (size_t)b * UN + u] = lst;
  }
}

extern "C" void kernel_launch(void* const* d_in, const int* in_sizes, int n_in,
                              void* d_out, int out_size, void* d_ws, size_t ws_size,
                              hipStream_t stream) {
  const float* inputs       = (const float*)d_in[0];
  const int*   dependencies = (const int*)d_in[1];
  const int*   mask         = (const int*)d_in[2];
  const float* initial      = (const float*)d_in[3];
  const float* Wz = (const float*)d_in[4];
  const float* Wr = (const float*)d_in[5];
  const float* Wh = (const float*)d_in[6];
  const float* Uz = (const float*)d_in[7];
  const float* Ur = (const float*)d_in[8];
  const float* Uh = (const float*)d_in[9];
  const float* bz = (const float*)d_in[10];
  const float* br = (const float*)d_in[11];
  const float* bh = (const float*)d_in[12];

  float* out = (float*)d_out;
  float* ws  = (float*)d_ws;
  float* wcat    = ws;                                   // 256*768
  float* bias    = wcat + (size_t)DN * NC;               // 768
  float* precomp = bias + NC;                            // B*T*768
  float* buf_s   = precomp + (size_t)BN * TN * NC;       // B*SLOTS*256 each
  float* buf_pr  = buf_s + (size_t)BN * SLOTS * UN;
  float* buf_pz  = buf_pr + (size_t)BN * SLOTS * UN;

  build_wcat<<<(DN * NC + 255) / 256, 256, 0, stream>>>(Wr, Wz, Wh, br, bz, bh, wcat, bias);
  gemm_xw<<<dim3(BN * TN / 64, NC / 64), 256, 0, stream>>>(inputs, wcat, bias, precomp);
  recurrent_kernel<<<BN, 1024, 0, stream>>>(precomp, Ur, Uz, Uh, dependencies, mask, initial,
                                            out, buf_s, buf_pr, buf_pz);
}